// Round 5
// baseline (22.067 us; speedup 1.0000x reference)
//
#include <hip/hip_runtime.h>
#include <hip/hip_bf16.h>

#define NB 16       // batch
#define NS 256      // tokens per row
#define ND 512      // feature dim
#define MAXDUR 10
#define TMAX (NS * MAXDUR)   // 2560
#define ND4 (ND / 4)         // 128 float4 per row
#define TB 32                // t-values per block
#define ITERS (TB * ND4 / 256)  // 16 float4 stores per thread

typedef float f32x4 __attribute__((ext_vector_type(4)));

// ---------------------------------------------------------------------------
// Single fused kernel. grid = (TMAX/TB, NB) = (80, 16), block = 256.
// Each block: load its row's durations, wave-shfl inclusive scan (LDS combine),
// binary-search its TB output frames, then stream TB*ND floats of output
// via nontemporal stores (write-once stream; keep x resident in L2).
// out[b,t,:] = (t < mel[b]) ? x[b, idx[b,t], :] : 0 ; mel_out[b] = mel (float)
// ---------------------------------------------------------------------------
__global__ __launch_bounds__(256) void la_fused_kernel(
    const f32x4* __restrict__ x,
    const int* __restrict__ dur,
    f32x4* __restrict__ out,
    float* __restrict__ mel_out) {
    __shared__ int s[NS];
    __shared__ int wsum[4];
    __shared__ int idx_s[TB];

    const int b    = blockIdx.y;
    const int tid  = threadIdx.x;
    const int lane = tid & 63;
    const int wid  = tid >> 6;

    // --- inclusive scan of durations (wave shfl + cross-wave LDS combine) ---
    int acc = dur[b * NS + tid];
    #pragma unroll
    for (int off = 1; off < 64; off <<= 1) {
        int n = __shfl_up(acc, off, 64);
        if (lane >= off) acc += n;
    }
    if (lane == 63) wsum[wid] = acc;
    __syncthreads();
    int add = 0;
    #pragma unroll
    for (int w = 0; w < 4; ++w)
        if (w < wid) add += wsum[w];
    acc += add;
    s[tid] = acc;
    __syncthreads();

    const int mel = s[NS - 1];
    if (blockIdx.x == 0 && tid == 0)
        mel_out[b] = (float)mel;    // second tuple output (float32)

    // --- searchsorted for this block's TB frames ---
    const int t0 = blockIdx.x * TB;
    if (tid < TB) {
        int t = t0 + tid;
        int lo = 0, hi = NS;
        while (lo < hi) {
            int mid = (lo + hi) >> 1;
            if (s[mid] > t) hi = mid; else lo = mid + 1;
        }
        idx_s[tid] = (lo < NS) ? lo : (NS - 1);
    }
    __syncthreads();

    // --- expand-gather: ITERS coalesced nontemporal float4 stores/thread ---
    const size_t outbase = ((size_t)b * TMAX + t0) * ND4;
    const size_t xbase   = (size_t)b * NS * ND4;
    #pragma unroll
    for (int k = 0; k < ITERS; ++k) {
        int item = k * 256 + tid;
        int tt   = item >> 7;            // local t in [0, TB)  (wave-uniform)
        int d4   = item & (ND4 - 1);
        f32x4 v = (f32x4)(0.f);
        if (t0 + tt < mel) {
            int src = idx_s[tt];         // LDS broadcast
            v = x[xbase + (size_t)src * ND4 + d4];
        }
        __builtin_nontemporal_store(v, &out[outbase + item]);
    }
}

extern "C" void kernel_launch(void* const* d_in, const int* in_sizes, int n_in,
                              void* d_out, int out_size, void* d_ws, size_t ws_size,
                              hipStream_t stream) {
    const float* x   = (const float*)d_in[0];
    const int*   dur = (const int*)d_in[1];

    float* out     = (float*)d_out;
    float* mel_out = out + (size_t)NB * TMAX * ND;   // tuple output 1 tail

    la_fused_kernel<<<dim3(TMAX / TB, NB), 256, 0, stream>>>(
        (const f32x4*)x, dur, (f32x4*)d_out, mel_out);
}

// Round 6
// 19.506 us; speedup vs baseline: 1.1313x; 1.1313x over previous
//
#include <hip/hip_runtime.h>
#include <hip/hip_bf16.h>

#define NB 16       // batch
#define NS 256      // tokens per row
#define ND 512      // feature dim
#define MAXDUR 10
#define TMAX (NS * MAXDUR)   // 2560
#define ND4 (ND / 4)         // 128 float4 per row
#define TB 32                // t-values per block
#define ITERS (TB * ND4 / 256)  // 16 float4 stores per thread
#define BLOCKS_PER_ROW (TMAX / TB)          // 80
#define NBLK (NB * BLOCKS_PER_ROW)          // 1280
#define NXCD 8
#define CHUNK (NBLK / NXCD)                 // 160 blocks per XCD = 2 batch rows

typedef float f32x4 __attribute__((ext_vector_type(4)));

// ---------------------------------------------------------------------------
// Single fused kernel. 1D grid of NBLK blocks, 256 threads.
// XCD-aware swizzle: consecutive hardware block ids round-robin across XCDs;
// we remap so each XCD owns a contiguous chunk = 2 full batch rows, keeping
// that XCD's x working set (1 MB) resident in its 4 MB L2.
// Each block: wave-shfl scan of its row's durations, binary-search its TB
// output frames, then stream TB*ND floats of coalesced output.
// out[b,t,:] = (t < mel[b]) ? x[b, idx[b,t], :] : 0 ; mel_out[b] = mel (float)
// ---------------------------------------------------------------------------
__global__ __launch_bounds__(256) void la_fused_kernel(
    const f32x4* __restrict__ x,
    const int* __restrict__ dur,
    f32x4* __restrict__ out,
    float* __restrict__ mel_out) {
    __shared__ int s[NS];
    __shared__ int wsum[4];
    __shared__ int idx_s[TB];

    // --- XCD-aware block swizzle (bijective: NBLK % NXCD == 0) ---
    const int bid = blockIdx.x;
    const int swz = (bid & (NXCD - 1)) * CHUNK + (bid >> 3);
    const int b   = swz / BLOCKS_PER_ROW;
    const int t0  = (swz - b * BLOCKS_PER_ROW) * TB;

    const int tid  = threadIdx.x;
    const int lane = tid & 63;
    const int wid  = tid >> 6;

    // --- inclusive scan of durations (wave shfl + cross-wave LDS combine) ---
    int acc = dur[b * NS + tid];
    #pragma unroll
    for (int off = 1; off < 64; off <<= 1) {
        int n = __shfl_up(acc, off, 64);
        if (lane >= off) acc += n;
    }
    if (lane == 63) wsum[wid] = acc;
    __syncthreads();
    int add = 0;
    #pragma unroll
    for (int w = 0; w < 4; ++w)
        if (w < wid) add += wsum[w];
    acc += add;
    s[tid] = acc;
    __syncthreads();

    const int mel = s[NS - 1];
    if (t0 == 0 && tid == 0)
        mel_out[b] = (float)mel;    // second tuple output (float32)

    // --- searchsorted for this block's TB frames ---
    if (tid < TB) {
        int t = t0 + tid;
        int lo = 0, hi = NS;
        while (lo < hi) {
            int mid = (lo + hi) >> 1;
            if (s[mid] > t) hi = mid; else lo = mid + 1;
        }
        idx_s[tid] = (lo < NS) ? lo : (NS - 1);
    }
    __syncthreads();

    // --- expand-gather: ITERS coalesced float4 stores per thread ---
    const size_t outbase = ((size_t)b * TMAX + t0) * ND4;
    const size_t xbase   = (size_t)b * NS * ND4;
    #pragma unroll
    for (int k = 0; k < ITERS; ++k) {
        int item = k * 256 + tid;
        int tt   = item >> 7;            // local t in [0, TB)  (wave-uniform)
        int d4   = item & (ND4 - 1);
        f32x4 v = (f32x4)(0.f);
        if (t0 + tt < mel) {
            int src = idx_s[tt];         // LDS broadcast
            v = x[xbase + (size_t)src * ND4 + d4];
        }
        out[outbase + item] = v;
    }
}

extern "C" void kernel_launch(void* const* d_in, const int* in_sizes, int n_in,
                              void* d_out, int out_size, void* d_ws, size_t ws_size,
                              hipStream_t stream) {
    const float* x   = (const float*)d_in[0];
    const int*   dur = (const int*)d_in[1];

    float* out     = (float*)d_out;
    float* mel_out = out + (size_t)NB * TMAX * ND;   // tuple output 1 tail

    la_fused_kernel<<<NBLK, 256, 0, stream>>>(
        (const f32x4*)x, dur, (f32x4*)d_out, mel_out);
}